// Round 1
// baseline (856.421 us; speedup 1.0000x reference)
//
#include <hip/hip_runtime.h>
#include <hip/hip_bf16.h>
#include <math.h>

#define N_NODES 100000
#define F_IN 512
#define H_DIM 16
#define C_DIM 40

// ---------------- fill / degree / rsqrt ----------------

__global__ void fill_kernel(float* __restrict__ p, float v, int n) {
    int i = blockIdx.x * blockDim.x + threadIdx.x;
    if (i < n) p[i] = v;
}

__global__ void deg_kernel(const int* __restrict__ dst, float* __restrict__ deg, int E) {
    int e = blockIdx.x * blockDim.x + threadIdx.x;
    if (e < E) atomicAdd(&deg[dst[e]], 1.0f);
}

__global__ void rsqrt_kernel(float* __restrict__ deg, int n) {
    int i = blockIdx.x * blockDim.x + threadIdx.x;
    if (i < n) {
        float d = deg[i];
        deg[i] = d > 0.0f ? rsqrtf(d) : 0.0f;
    }
}

// ---------------- GEMM1: h1 = x @ W1  (one thread per row) ----------------

__global__ void __launch_bounds__(256) gemm1_kernel(const float* __restrict__ x,
                                                    const float* __restrict__ W1,
                                                    float* __restrict__ h1, int N) {
    __shared__ float w[F_IN * H_DIM];  // 32 KB
    {
        float4* w4 = (float4*)w;
        const float4* W4 = (const float4*)W1;
        for (int i = threadIdx.x; i < F_IN * H_DIM / 4; i += 256) w4[i] = W4[i];
    }
    __syncthreads();
    int row = blockIdx.x * 256 + threadIdx.x;
    if (row >= N) return;
    const float4* xr = (const float4*)(x + (size_t)row * F_IN);
    float acc[H_DIM];
#pragma unroll
    for (int k = 0; k < H_DIM; k++) acc[k] = 0.0f;
    for (int f4 = 0; f4 < F_IN / 4; ++f4) {
        float4 xv = xr[f4];
        const float* wp = &w[f4 * 4 * H_DIM];
#pragma unroll
        for (int k = 0; k < H_DIM; k++) acc[k] += xv.x * wp[k];
#pragma unroll
        for (int k = 0; k < H_DIM; k++) acc[k] += xv.y * wp[H_DIM + k];
#pragma unroll
        for (int k = 0; k < H_DIM; k++) acc[k] += xv.z * wp[2 * H_DIM + k];
#pragma unroll
        for (int k = 0; k < H_DIM; k++) acc[k] += xv.w * wp[3 * H_DIM + k];
    }
    float4* o = (float4*)(h1 + (size_t)row * H_DIM);
    o[0] = make_float4(acc[0], acc[1], acc[2], acc[3]);
    o[1] = make_float4(acc[4], acc[5], acc[6], acc[7]);
    o[2] = make_float4(acc[8], acc[9], acc[10], acc[11]);
    o[3] = make_float4(acc[12], acc[13], acc[14], acc[15]);
}

// ---------------- edge scatter in 16-dim space (used for both layers) ----------------

__global__ void scatter16_kernel(const int* __restrict__ src, const int* __restrict__ dst,
                                 const float* __restrict__ dinv, const float* __restrict__ h,
                                 float* __restrict__ acc, int E) {
    int t = blockIdx.x * blockDim.x + threadIdx.x;
    int e = t >> 4;
    if (e >= E) return;
    int k = t & 15;
    int s = src[e];
    int d = dst[e];
    float norm = dinv[s] * dinv[d];
    atomicAdd(&acc[(size_t)d * H_DIM + k], h[(size_t)s * H_DIM + k] * norm);
}

// ---------------- epilogue 1: add self-loop + bias, ReLU ----------------

__global__ void epi1_kernel(const float* __restrict__ acc, const float* __restrict__ h1,
                            const float* __restrict__ dinv, const float* __restrict__ b1,
                            float* __restrict__ hb, int N) {
    int t = blockIdx.x * blockDim.x + threadIdx.x;
    int n = t >> 4;
    if (n >= N) return;
    int k = t & 15;
    float di = dinv[n];
    float v = acc[t] + h1[t] * di * di + b1[k];
    hb[t] = fmaxf(v, 0.0f);
}

// ---------------- final: self-loop + @W2 + b2, log_softmax, write both outputs ----------------

__global__ void __launch_bounds__(256) final_kernel(const float* __restrict__ acc,
                                                    const float* __restrict__ hb,
                                                    const float* __restrict__ dinv,
                                                    const float* __restrict__ W2,
                                                    const float* __restrict__ b2,
                                                    float* __restrict__ out, int N) {
    __shared__ float w2s[H_DIM * C_DIM];
    __shared__ float b2s[C_DIM];
    for (int i = threadIdx.x; i < H_DIM * C_DIM; i += 256) w2s[i] = W2[i];
    if (threadIdx.x < C_DIM) b2s[threadIdx.x] = b2[threadIdx.x];
    __syncthreads();
    int n = blockIdx.x * 256 + threadIdx.x;
    if (n >= N) return;
    float di = dinv[n];
    float di2 = di * di;
    float v[H_DIM];
#pragma unroll
    for (int k = 0; k < H_DIM; k++) {
        int t = n * H_DIM + k;
        v[k] = acc[t] + hb[t] * di2;
    }
    float lg[C_DIM];
    float m = -1e30f;
    for (int c = 0; c < C_DIM; c++) {
        float a = b2s[c];
#pragma unroll
        for (int k = 0; k < H_DIM; k++) a += v[k] * w2s[k * C_DIM + c];
        lg[c] = a;
        m = fmaxf(m, a);
    }
    float ssum = 0.0f;
    for (int c = 0; c < C_DIM; c++) ssum += __expf(lg[c] - m);
    float lse = m + __logf(ssum);
    float* o1 = out + (size_t)n * C_DIM;
    float* o2 = out + (size_t)N_NODES * C_DIM + (size_t)n * C_DIM;
    for (int c = 0; c < C_DIM; c++) {
        o1[c] = lg[c] - lse;
        o2[c] = lg[c];
    }
}

// ---------------- launch ----------------

extern "C" void kernel_launch(void* const* d_in, const int* in_sizes, int n_in,
                              void* d_out, int out_size, void* d_ws, size_t ws_size,
                              hipStream_t stream) {
    const float* x  = (const float*)d_in[0];
    const int* ei   = (const int*)d_in[1];
    const float* W1 = (const float*)d_in[2];
    const float* b1 = (const float*)d_in[3];
    const float* W2 = (const float*)d_in[4];
    const float* b2 = (const float*)d_in[5];
    float* out = (float*)d_out;

    const int N = N_NODES;
    const int E = in_sizes[1] / 2;
    const int* src = ei;
    const int* dst = ei + E;

    // workspace layout (floats): dinv[N] | h1[16N] | hb[16N] | accA[16N] | accB[16N]
    float* ws   = (float*)d_ws;
    float* dinv = ws;
    float* h1   = ws + N;
    float* hb   = h1 + 16 * N;
    float* accA = hb + 16 * N;
    float* accB = accA + 16 * N;

    // accA and accB are contiguous: one memset for both
    hipMemsetAsync(accA, 0, (size_t)32 * N * sizeof(float), stream);

    // degree (init 1.0 for self-loop), then dinv = rsqrt(deg) in place
    fill_kernel<<<(N + 255) / 256, 256, 0, stream>>>(dinv, 1.0f, N);
    deg_kernel<<<(E + 255) / 256, 256, 0, stream>>>(dst, dinv, E);
    rsqrt_kernel<<<(N + 255) / 256, 256, 0, stream>>>(dinv, N);

    // layer 1
    gemm1_kernel<<<(N + 255) / 256, 256, 0, stream>>>(x, W1, h1, N);
    scatter16_kernel<<<(E * 16 + 255) / 256, 256, 0, stream>>>(src, dst, dinv, h1, accA, E);
    epi1_kernel<<<(N * 16 + 255) / 256, 256, 0, stream>>>(accA, h1, dinv, b1, hb, N);

    // layer 2: aggregate in 16-dim hidden space (A(h@W2) == (A h)@W2), W2 applied in epilogue
    scatter16_kernel<<<(E * 16 + 255) / 256, 256, 0, stream>>>(src, dst, dinv, hb, accB, E);
    final_kernel<<<(N + 255) / 256, 256, 0, stream>>>(accB, hb, dinv, W2, b2, out, N);
}